// Round 1
// baseline (978.264 us; speedup 1.0000x reference)
//
#include <hip/hip_runtime.h>
#include <hip/hip_bf16.h>
#include <cmath>

// Problem constants (match reference)
#define NF 64
#define GRP 8
#define CG 8          // NF / GRP
#define KK 9
#define HH 128
#define WWID 128
#define BB 4
#define HWSZ (HH * WWID)
#define C_OM 216      // 3 * GRP * KK

// ---------------------------------------------------------------------------
// Direct 3x3 conv, stride 1, pad 1. 16x16 output-pixel tile per block,
// COUT chunked across blockIdx.y, input channels staged through LDS 4 at a
// time. Weights are read with thread-uniform indices -> scalar loads.
// ---------------------------------------------------------------------------
template <int CIN, int CHUNK, bool CONCAT, bool LRELU>
__global__ __launch_bounds__(256) void conv3x3_kernel(
    const float* __restrict__ srcA, const float* __restrict__ srcB,
    const float* __restrict__ wgt, const float* __restrict__ bias,
    float* __restrict__ dst, int cout_total)
{
    constexpr int SC = 4;
    __shared__ float patch[SC * 18 * 18];

    const int tid = threadIdx.x;
    const int tile = blockIdx.x;            // 0..63  (8x8 tiles of 16x16)
    const int tx = tile & 7, ty = tile >> 3;
    const int x0 = tx * 16, y0 = ty * 16;
    const int o0 = blockIdx.y * CHUNK;
    const int b  = blockIdx.z;
    const int px = tid & 15, py = tid >> 4;

    float acc[CHUNK];
#pragma unroll
    for (int o = 0; o < CHUNK; ++o) acc[o] = bias[o0 + o];

    for (int c0 = 0; c0 < CIN; c0 += SC) {
        __syncthreads();
        for (int i = tid; i < SC * 324; i += 256) {
            int c = i / 324, rem = i - c * 324;
            int r = rem / 18, col = rem - r * 18;
            int gy = y0 + r - 1, gx = x0 + col - 1;
            float v = 0.f;
            if ((unsigned)gy < HH && (unsigned)gx < WWID) {
                int cc = c0 + c;
                const float* s;
                if (CONCAT) {
                    s = (cc < NF) ? (srcA + ((size_t)b * NF + cc) * HWSZ)
                                  : (srcB + ((size_t)b * NF + (cc - NF)) * HWSZ);
                } else {
                    s = srcA + ((size_t)b * CIN + cc) * HWSZ;
                }
                v = s[gy * WWID + gx];
            }
            patch[i] = v;
        }
        __syncthreads();
#pragma unroll
        for (int c = 0; c < SC; ++c) {
            float pv[9];
#pragma unroll
            for (int t = 0; t < 9; ++t)
                pv[t] = patch[c * 324 + (py + t / 3) * 18 + (px + t % 3)];
            const float* wbase = wgt + ((size_t)o0 * CIN + (c0 + c)) * 9;
#pragma unroll
            for (int o = 0; o < CHUNK; ++o) {
                const float* w9 = wbase + (size_t)o * CIN * 9;
#pragma unroll
                for (int t = 0; t < 9; ++t)
                    acc[o] = fmaf(pv[t], w9[t], acc[o]);
            }
        }
    }

    const int gy = y0 + py, gx = x0 + px;
#pragma unroll
    for (int o = 0; o < CHUNK; ++o) {
        float v = acc[o];
        if (LRELU) v = (v >= 0.f) ? v : 0.1f * v;
        dst[(((size_t)b * cout_total + o0 + o) * HH + gy) * WWID + gx] = v;
    }
}

// ---------------------------------------------------------------------------
// Repack w_dcn [NF][NF][3][3] -> wp[(g*9+k)*8*64 + c*64 + o]
// so the DCN inner loop reads 64 contiguous floats (scalar-load friendly).
// ---------------------------------------------------------------------------
__global__ void repack_kernel(const float* __restrict__ w, float* __restrict__ wp)
{
    int i = blockIdx.x * 256 + threadIdx.x;
    if (i >= NF * NF * KK) return;
    int o  = i & 63;
    int c  = (i >> 6) & 7;
    int gk = i >> 9;          // g*9 + k
    int g  = gk / 9, k = gk - g * 9;
    wp[i] = w[((size_t)o * NF + g * CG + c) * KK + k];
}

// ---------------------------------------------------------------------------
// Deformable sampling + modulation + einsum + bias + lrelu.
// Block = 128 threads: wave0 handles groups 0..3, wave1 groups 4..7 for the
// same 64 consecutive pixels; partials combined through LDS.
// ---------------------------------------------------------------------------
__global__ __launch_bounds__(128) void dcn_kernel(
    const float* __restrict__ nbr, const float* __restrict__ om,
    const float* __restrict__ wp, const float* __restrict__ bdcn,
    float* __restrict__ out)
{
    __shared__ float red[64][72];

    const int tid = threadIdx.x;
    const int p   = tid & 63;
    const int hf  = __builtin_amdgcn_readfirstlane(tid >> 6);
    const int blk = blockIdx.x;           // 0..1023
    const int b   = blk >> 8;             // 256 blocks per batch image
    const int rem = blk & 255;
    const int y   = rem >> 1;
    const int x   = ((rem & 1) << 6) + p;

    float acc[NF];
#pragma unroll
    for (int o = 0; o < NF; ++o) acc[o] = 0.f;

    const float* omb = om + (size_t)b * C_OM * HWSZ + (size_t)y * WWID + x;
    const float* nbb = nbr + (size_t)b * NF * HWSZ;

    for (int gg = 0; gg < 4; ++gg) {
        const int g = hf * 4 + gg;
#pragma unroll
        for (int k = 0; k < 9; ++k) {
            const int ch = g * 9 + k;
            float oy = omb[(size_t)ch * HWSZ];
            float ox = omb[(size_t)(72 + ch) * HWSZ];
            float mr = omb[(size_t)(144 + ch) * HWSZ];
            float mv = 1.f / (1.f + __expf(-mr));

            float pyf = (float)y + (float)(k / 3 - 1) + oy;
            float pxf = (float)x + (float)(k % 3 - 1) + ox;
            float fy = floorf(pyf), fx = floorf(pxf);
            float wy = pyf - fy, wx = pxf - fx;
            int iy = (int)fy, ix = (int)fx;

            float w00 = (1.f - wy) * (1.f - wx);
            float w01 = (1.f - wy) * wx;
            float w10 = wy * (1.f - wx);
            float w11 = wy * wx;

            bool vy0 = (iy >= 0) && (iy < HH);
            bool vy1 = (iy + 1 >= 0) && (iy + 1 < HH);
            bool vx0 = (ix >= 0) && (ix < WWID);
            bool vx1 = (ix + 1 >= 0) && (ix + 1 < WWID);
            w00 *= (vy0 && vx0) ? mv : 0.f;
            w01 *= (vy0 && vx1) ? mv : 0.f;
            w10 *= (vy1 && vx0) ? mv : 0.f;
            w11 *= (vy1 && vx1) ? mv : 0.f;

            int y0c = min(max(iy, 0), HH - 1);
            int y1c = min(max(iy + 1, 0), HH - 1);
            int x0c = min(max(ix, 0), WWID - 1);
            int x1c = min(max(ix + 1, 0), WWID - 1);
            int i00 = y0c * WWID + x0c, i01 = y0c * WWID + x1c;
            int i10 = y1c * WWID + x0c, i11 = y1c * WWID + x1c;

            const float* ng = nbb + (size_t)(g * CG) * HWSZ;
            float sval[CG];
#pragma unroll
            for (int c = 0; c < CG; ++c) {
                const float* nc = ng + (size_t)c * HWSZ;
                sval[c] = w00 * nc[i00] + w01 * nc[i01] + w10 * nc[i10] + w11 * nc[i11];
            }

            const float* wc = wp + (size_t)((g * 9 + k) * CG) * NF;
#pragma unroll
            for (int c = 0; c < CG; ++c) {
#pragma unroll
                for (int o = 0; o < NF; ++o)
                    acc[o] = fmaf(sval[c], wc[c * NF + o], acc[o]);
            }
        }
    }

    if (hf == 1) {
#pragma unroll
        for (int o = 0; o < NF; o += 4)
            *(float4*)&red[p][o] = *(float4*)&acc[o];
    }
    __syncthreads();
    if (hf == 0) {
        const size_t ob = (size_t)b * NF * HWSZ + (size_t)y * WWID + x;
#pragma unroll
        for (int o = 0; o < NF; ++o) {
            float v = acc[o] + red[p][o] + bdcn[o];
            v = (v >= 0.f) ? v : 0.1f * v;
            out[ob + (size_t)o * HWSZ] = v;
        }
    }
}

// ---------------------------------------------------------------------------
extern "C" void kernel_launch(void* const* d_in, const int* in_sizes, int n_in,
                              void* d_out, int out_size, void* d_ws, size_t ws_size,
                              hipStream_t stream)
{
    const float* nbr  = (const float*)d_in[0];
    const float* ref  = (const float*)d_in[1];
    const float* w1   = (const float*)d_in[2];
    const float* b1   = (const float*)d_in[3];
    const float* wom  = (const float*)d_in[4];
    const float* bom  = (const float*)d_in[5];
    const float* wdcn = (const float*)d_in[6];
    const float* bdcn = (const float*)d_in[7];
    float* out = (float*)d_out;

    float* off_feat = (float*)d_ws;                                  // B*64*HW
    float* om       = off_feat + (size_t)BB * NF * HWSZ;             // B*216*HW
    float* wp       = om + (size_t)BB * C_OM * HWSZ;                 // 36864

    // conv1: concat(nbr, ref) 128ch -> 64ch, + lrelu
    dim3 g1(64, NF / 32, BB);
    conv3x3_kernel<128, 32, true, true><<<g1, 256, 0, stream>>>(
        nbr, ref, w1, b1, off_feat, NF);

    // conv_om: 64ch -> 216ch, no activation
    dim3 g2(64, C_OM / 24, BB);
    conv3x3_kernel<64, 24, false, false><<<g2, 256, 0, stream>>>(
        off_feat, nullptr, wom, bom, om, C_OM);

    // repack dcn weights
    repack_kernel<<<(NF * NF * KK + 255) / 256, 256, 0, stream>>>(wdcn, wp);

    // deformable conv
    dcn_kernel<<<BB * HH * WWID / 64, 128, 0, stream>>>(nbr, om, wp, bdcn, out);
}

// Round 2
// 401.127 us; speedup vs baseline: 2.4388x; 2.4388x over previous
//
#include <hip/hip_runtime.h>
#include <hip/hip_bf16.h>
#include <cmath>

// Problem constants (match reference)
#define NF 64
#define GRP 8
#define CG 8          // NF / GRP
#define KK 9
#define HH 128
#define WWID 128
#define BB 4
#define HWSZ (HH * WWID)
#define C_OM 216      // 3 * GRP * KK

typedef __attribute__((ext_vector_type(8))) short bf16x8;
typedef __attribute__((ext_vector_type(4))) float f32x4;

__device__ inline unsigned short f2bf(float f) {
    union { float f; unsigned u; } x; x.f = f;
    unsigned r = x.u + 0x7fff + ((x.u >> 16) & 1);   // RNE
    return (unsigned short)(r >> 16);
}

// ---------------------------------------------------------------------------
// NCHW fp32 (nbr ++ ref) -> NHWC bf16 [B][H][W][128], LDS-tiled transpose.
// Block handles one 64-pixel row segment x 128 channels.
// ---------------------------------------------------------------------------
__global__ __launch_bounds__(256) void to_nhwc_kernel(
    const float* __restrict__ nbr, const float* __restrict__ ref,
    unsigned short* __restrict__ out)
{
    __shared__ unsigned short lds[64 * 132];
    const int tid = threadIdx.x, blk = blockIdx.x;
    const int b = blk >> 8, rem = blk & 255, y = rem >> 1, x0 = (rem & 1) * 64;
    const size_t rowoff = (size_t)y * WWID + x0;

    for (int it = 0; it < 32; ++it) {
        int idx = it * 256 + tid;
        int c = idx >> 6, p = idx & 63;
        const float* src = (c < NF) ? (nbr + (size_t)(b * NF + c) * HWSZ)
                                    : (ref + (size_t)(b * NF + c - NF) * HWSZ);
        lds[p * 132 + c] = f2bf(src[rowoff + p]);
    }
    __syncthreads();
    const int p = tid >> 2, c0 = (tid & 3) * 32;
    unsigned short* dst = out + ((size_t)b * HWSZ + rowoff + p) * 128 + c0;
#pragma unroll
    for (int i = 0; i < 8; ++i)
        *(int2*)(dst + i * 4) = *(const int2*)&lds[p * 132 + c0 + i * 4];
}

// ---------------------------------------------------------------------------
// Repack conv weights OIHW fp32 -> MFMA A-fragment order, bf16:
// wf[((kt*MT + mt)*64 + lane)*8 + j], kt = (cin0/32)*9 + tap,
// A[row=cout=mt*16+(lane&15)][k=cin0+(lane>>4)*8+j] for tap (ky*3+kx).
// ---------------------------------------------------------------------------
template <int CIN, int COUT, int MT>
__global__ void repack_conv_kernel(const float* __restrict__ w,
                                   unsigned short* __restrict__ wf)
{
    constexpr int KT = (CIN / 32) * 9;
    int idx = blockIdx.x * 256 + threadIdx.x;
    if (idx >= KT * MT * 512) return;
    int j = idx & 7, lane = (idx >> 3) & 63, t = idx >> 9;
    int mt = t % MT, kt = t / MT;
    int c0 = (kt / 9) * 32, tap = kt - (kt / 9) * 9;
    int cout = mt * 16 + (lane & 15);
    int cin = c0 + ((lane >> 4) * 8) + j;
    float v = (cout < COUT) ? w[((size_t)cout * CIN + cin) * KK + tap] : 0.f;
    wf[idx] = f2bf(v);
}

// ---------------------------------------------------------------------------
// Implicit-GEMM 3x3 conv via mfma_f32_16x16x32_bf16.
// Wave tile: M=64 couts x N=64 pixels (one row segment). No LDS, no barriers.
// MGROUPS=1: 4 waves take 4 consecutive row segments (grid/4 blocks).
// MGROUPS=4: 4 waves split 256 padded couts over the same segment.
// ---------------------------------------------------------------------------
template <int CIN, int MGROUPS, int COUT, bool LRELU, bool OUTBF16>
__global__ __launch_bounds__(256) void conv_mfma_kernel(
    const unsigned short* __restrict__ in,   // NHWC bf16 [B][H][W][CIN]
    const unsigned short* __restrict__ wf,   // swizzled fragments
    const float* __restrict__ bias,
    void* __restrict__ dstv)
{
    const int tid = threadIdx.x;
    const int lane = tid & 63;
    const int wv = tid >> 6;
    const int mg = (MGROUPS == 1) ? 0 : wv;
    const int ng = (MGROUPS == 1) ? (blockIdx.x * 4 + wv) : blockIdx.x;
    const int x0 = (ng & 1) * 64;
    const int y  = (ng >> 1) & 127;
    const int b  = ng >> 8;
    const int ln = lane & 15, kb = lane >> 4;
    constexpr int MT = MGROUPS * 4;

    f32x4 acc[4][4];
#pragma unroll
    for (int i = 0; i < 4; ++i)
#pragma unroll
        for (int j = 0; j < 4; ++j) acc[i][j] = f32x4{0.f, 0.f, 0.f, 0.f};

    const unsigned short* inb = in + (size_t)b * HWSZ * CIN + (size_t)kb * 8;

    for (int c0 = 0; c0 < CIN; c0 += 32) {
#pragma unroll
        for (int tap = 0; tap < 9; ++tap) {
            const int ky = tap / 3, kx = tap % 3;
            const int yy = y + ky - 1;
            const bool rowv = (unsigned)yy < (unsigned)HH;
            const int yc = rowv ? yy : 0;
            const unsigned short* rowp = inb + (size_t)yc * WWID * CIN + c0;
            bf16x8 bfrag[4];
#pragma unroll
            for (int nt = 0; nt < 4; ++nt) {
                int xx = x0 + nt * 16 + ln + kx - 1;
                bool v = rowv && ((unsigned)xx < (unsigned)WWID);
                int xc = v ? xx : 0;
                int4 t = *(const int4*)(rowp + (size_t)xc * CIN);
                if (!v) { t.x = 0; t.y = 0; t.z = 0; t.w = 0; }
                bfrag[nt] = *(bf16x8*)&t;
            }
            const int kt = (c0 / 32) * 9 + tap;
            const bf16x8* af = (const bf16x8*)wf + ((size_t)kt * MT + mg * 4) * 64 + lane;
            bf16x8 afrag[4];
#pragma unroll
            for (int mt = 0; mt < 4; ++mt) afrag[mt] = af[(size_t)mt * 64];
#pragma unroll
            for (int mt = 0; mt < 4; ++mt)
#pragma unroll
                for (int nt = 0; nt < 4; ++nt)
                    acc[mt][nt] = __builtin_amdgcn_mfma_f32_16x16x32_bf16(
                        afrag[mt], bfrag[nt], acc[mt][nt], 0, 0, 0);
        }
    }

    // Epilogue: D col=lane&15 (pixel), row=(lane>>4)*4+reg (cout) -> couts
    // contiguous per lane, NHWC store.
#pragma unroll
    for (int mt = 0; mt < 4; ++mt) {
        const int cout = mg * 64 + mt * 16 + kb * 4;
        if (cout >= COUT) continue;
        const float b0 = bias[cout], b1 = bias[cout + 1];
        const float b2 = bias[cout + 2], b3 = bias[cout + 3];
#pragma unroll
        for (int nt = 0; nt < 4; ++nt) {
            const int px = x0 + nt * 16 + ln;
            const size_t pix = (size_t)b * HWSZ + (size_t)y * WWID + px;
            f32x4 v = acc[mt][nt];
            v[0] += b0; v[1] += b1; v[2] += b2; v[3] += b3;
            if (LRELU) {
#pragma unroll
                for (int r = 0; r < 4; ++r) v[r] = (v[r] >= 0.f) ? v[r] : 0.1f * v[r];
            }
            if (OUTBF16) {
                unsigned short* dst = (unsigned short*)dstv + pix * COUT + cout;
                int2 pk;
                pk.x = (int)f2bf(v[0]) | ((int)f2bf(v[1]) << 16);
                pk.y = (int)f2bf(v[2]) | ((int)f2bf(v[3]) << 16);
                *(int2*)dst = pk;
            } else {
                float* dst = (float*)dstv + pix * COUT + cout;
                *(f32x4*)dst = v;
            }
        }
    }
}

// ---------------------------------------------------------------------------
// Repack w_dcn [NF][NF][3][3] -> wp[(g*9+k)*8*64 + c*64 + o]
// ---------------------------------------------------------------------------
__global__ void repack_dcn_kernel(const float* __restrict__ w, float* __restrict__ wp)
{
    int i = blockIdx.x * 256 + threadIdx.x;
    if (i >= NF * NF * KK) return;
    int o  = i & 63;
    int c  = (i >> 6) & 7;
    int gk = i >> 9;          // g*9 + k
    int g  = gk / 9, k = gk - g * 9;
    wp[i] = w[((size_t)o * NF + g * CG + c) * KK + k];
}

// ---------------------------------------------------------------------------
// Deformable sampling + modulation + einsum + bias + lrelu.
// om is NHWC fp32 [B][H][W][216]. nbr stays NCHW fp32. out NCHW fp32.
// ---------------------------------------------------------------------------
__global__ __launch_bounds__(128) void dcn_kernel(
    const float* __restrict__ nbr, const float* __restrict__ om,
    const float* __restrict__ wp, const float* __restrict__ bdcn,
    float* __restrict__ out)
{
    __shared__ float red[64][72];

    const int tid = threadIdx.x;
    const int p   = tid & 63;
    const int hf  = __builtin_amdgcn_readfirstlane(tid >> 6);
    const int blk = blockIdx.x;           // 0..1023
    const int b   = blk >> 8;
    const int rem = blk & 255;
    const int y   = rem >> 1;
    const int x   = ((rem & 1) << 6) + p;

    float acc[NF];
#pragma unroll
    for (int o = 0; o < NF; ++o) acc[o] = 0.f;

    const float* omp = om + ((size_t)(b * HH + y) * WWID + x) * C_OM;
    const float* nbb = nbr + (size_t)b * NF * HWSZ;

    for (int gg = 0; gg < 4; ++gg) {
        const int g = hf * 4 + gg;
#pragma unroll
        for (int k = 0; k < 9; ++k) {
            const int ch = g * 9 + k;
            float oy = omp[ch];
            float ox = omp[72 + ch];
            float mr = omp[144 + ch];
            float mv = 1.f / (1.f + __expf(-mr));

            float pyf = (float)y + (float)(k / 3 - 1) + oy;
            float pxf = (float)x + (float)(k % 3 - 1) + ox;
            float fy = floorf(pyf), fx = floorf(pxf);
            float wy = pyf - fy, wx = pxf - fx;
            int iy = (int)fy, ix = (int)fx;

            float w00 = (1.f - wy) * (1.f - wx);
            float w01 = (1.f - wy) * wx;
            float w10 = wy * (1.f - wx);
            float w11 = wy * wx;

            bool vy0 = (iy >= 0) && (iy < HH);
            bool vy1 = (iy + 1 >= 0) && (iy + 1 < HH);
            bool vx0 = (ix >= 0) && (ix < WWID);
            bool vx1 = (ix + 1 >= 0) && (ix + 1 < WWID);
            w00 *= (vy0 && vx0) ? mv : 0.f;
            w01 *= (vy0 && vx1) ? mv : 0.f;
            w10 *= (vy1 && vx0) ? mv : 0.f;
            w11 *= (vy1 && vx1) ? mv : 0.f;

            int y0c = min(max(iy, 0), HH - 1);
            int y1c = min(max(iy + 1, 0), HH - 1);
            int x0c = min(max(ix, 0), WWID - 1);
            int x1c = min(max(ix + 1, 0), WWID - 1);
            int i00 = y0c * WWID + x0c, i01 = y0c * WWID + x1c;
            int i10 = y1c * WWID + x0c, i11 = y1c * WWID + x1c;

            const float* ng = nbb + (size_t)(g * CG) * HWSZ;
            float sval[CG];
#pragma unroll
            for (int c = 0; c < CG; ++c) {
                const float* nc = ng + (size_t)c * HWSZ;
                sval[c] = w00 * nc[i00] + w01 * nc[i01] + w10 * nc[i10] + w11 * nc[i11];
            }

            const float* wc = wp + (size_t)((g * 9 + k) * CG) * NF;
#pragma unroll
            for (int c = 0; c < CG; ++c) {
#pragma unroll
                for (int o = 0; o < NF; ++o)
                    acc[o] = fmaf(sval[c], wc[c * NF + o], acc[o]);
            }
        }
    }

    if (hf == 1) {
#pragma unroll
        for (int o = 0; o < NF; o += 4)
            *(float4*)&red[p][o] = *(float4*)&acc[o];
    }
    __syncthreads();
    if (hf == 0) {
        const size_t ob = (size_t)b * NF * HWSZ + (size_t)y * WWID + x;
#pragma unroll
        for (int o = 0; o < NF; ++o) {
            float v = acc[o] + red[p][o] + bdcn[o];
            v = (v >= 0.f) ? v : 0.1f * v;
            out[ob + (size_t)o * HWSZ] = v;
        }
    }
}

// ---------------------------------------------------------------------------
extern "C" void kernel_launch(void* const* d_in, const int* in_sizes, int n_in,
                              void* d_out, int out_size, void* d_ws, size_t ws_size,
                              hipStream_t stream)
{
    const float* nbr  = (const float*)d_in[0];
    const float* ref  = (const float*)d_in[1];
    const float* w1   = (const float*)d_in[2];
    const float* b1   = (const float*)d_in[3];
    const float* wom  = (const float*)d_in[4];
    const float* bom  = (const float*)d_in[5];
    const float* wdcn = (const float*)d_in[6];
    const float* bdcn = (const float*)d_in[7];
    float* out = (float*)d_out;

    // Workspace layout (bytes). nhwcin aliases om: nhwcin is dead before
    // conv_om writes om (same stream ordering, deterministic).
    char* ws = (char*)d_ws;
    const size_t OM_BYTES  = (size_t)BB * HWSZ * C_OM * 4;      // 56,623,104
    const size_t OFF_BYTES = (size_t)BB * HWSZ * NF * 2;        //  8,388,608
    unsigned short* nhwcin = (unsigned short*)ws;                // bf16 [B][H][W][128]
    float*          om     = (float*)ws;                         // fp32 [B][H][W][216]
    unsigned short* off_f  = (unsigned short*)(ws + OM_BYTES);   // bf16 [B][H][W][64]
    unsigned short* wf1    = (unsigned short*)(ws + OM_BYTES + OFF_BYTES);
    unsigned short* wf2    = wf1 + 36 * 4 * 512;                 // 73,728 elems
    float*          wp     = (float*)(wf2 + 18 * 16 * 512);     // after 147,456 elems

    // 1) concat + transpose to NHWC bf16
    to_nhwc_kernel<<<BB * HH * 2, 256, 0, stream>>>(nbr, ref, nhwcin);

    // 2) weight repacks
    repack_conv_kernel<128, NF, 4><<<(36 * 4 * 512 + 255) / 256, 256, 0, stream>>>(w1, wf1);
    repack_conv_kernel<64, C_OM, 16><<<(18 * 16 * 512 + 255) / 256, 256, 0, stream>>>(wom, wf2);
    repack_dcn_kernel<<<(NF * NF * KK + 255) / 256, 256, 0, stream>>>(wdcn, wp);

    // 3) conv1: 128ch -> 64ch + lrelu, NHWC bf16 out
    conv_mfma_kernel<128, 1, NF, true, true><<<BB * HH * 2 / 4, 256, 0, stream>>>(
        nhwcin, wf1, b1, off_f);

    // 4) conv_om: 64ch -> 216ch (padded 256), NHWC fp32 out
    conv_mfma_kernel<64, 4, C_OM, false, false><<<BB * HH * 2, 256, 0, stream>>>(
        off_f, wf2, bom, om);

    // 5) deformable conv
    dcn_kernel<<<BB * HH * WWID / 64, 128, 0, stream>>>(nbr, om, wp, bdcn, out);
}

// Round 3
// 184.002 us; speedup vs baseline: 5.3166x; 2.1800x over previous
//
#include <hip/hip_runtime.h>
#include <hip/hip_bf16.h>
#include <cmath>

#define NF 64
#define GRP 8
#define CG 8
#define KK 9
#define HH 128
#define WWID 128
#define BB 4
#define HWSZ (HH * WWID)
#define C_OM 216

typedef __attribute__((ext_vector_type(8))) short bf16x8;
typedef __attribute__((ext_vector_type(4))) float f32x4;

__device__ inline unsigned short f2bf(float f) {
    union { float f; unsigned u; } x; x.f = f;
    unsigned r = x.u + 0x7fff + ((x.u >> 16) & 1);   // RNE
    return (unsigned short)(r >> 16);
}
__device__ inline float bf2f(unsigned short s) {
    union { unsigned u; float f; } x; x.u = ((unsigned)s) << 16; return x.f;
}

// ---------------------------------------------------------------------------
// NCHW fp32 (nbr ++ ref) -> NHWC bf16 [B][H][W][128]
// ---------------------------------------------------------------------------
__global__ __launch_bounds__(256) void to_nhwc_kernel(
    const float* __restrict__ nbr, const float* __restrict__ ref,
    unsigned short* __restrict__ out)
{
    __shared__ unsigned short lds[64 * 132];
    const int tid = threadIdx.x, blk = blockIdx.x;
    const int b = blk >> 8, rem = blk & 255, y = rem >> 1, x0 = (rem & 1) * 64;
    const size_t rowoff = (size_t)y * WWID + x0;

    for (int it = 0; it < 32; ++it) {
        int idx = it * 256 + tid;
        int c = idx >> 6, p = idx & 63;
        const float* src = (c < NF) ? (nbr + (size_t)(b * NF + c) * HWSZ)
                                    : (ref + (size_t)(b * NF + c - NF) * HWSZ);
        lds[p * 132 + c] = f2bf(src[rowoff + p]);
    }
    __syncthreads();
    const int p = tid >> 2, c0 = (tid & 3) * 32;
    unsigned short* dst = out + ((size_t)b * HWSZ + rowoff + p) * 128 + c0;
#pragma unroll
    for (int i = 0; i < 8; ++i)
        *(int2*)(dst + i * 4) = *(const int2*)&lds[p * 132 + c0 + i * 4];
}

// ---------------------------------------------------------------------------
// Conv weight repack OIHW fp32 -> A-fragment bf16
// ---------------------------------------------------------------------------
template <int CIN, int COUT, int MT>
__global__ void repack_conv_kernel(const float* __restrict__ w,
                                   unsigned short* __restrict__ wf)
{
    constexpr int KT = (CIN / 32) * 9;
    int idx = blockIdx.x * 256 + threadIdx.x;
    if (idx >= KT * MT * 512) return;
    int j = idx & 7, lane = (idx >> 3) & 63, t = idx >> 9;
    int mt = t % MT, kt = t / MT;
    int c0 = (kt / 9) * 32, tap = kt - (kt / 9) * 9;
    int cout = mt * 16 + (lane & 15);
    int cin = c0 + ((lane >> 4) * 8) + j;
    float v = (cout < COUT) ? w[((size_t)cout * CIN + cin) * KK + tap] : 0.f;
    wf[idx] = f2bf(v);
}

// ---------------------------------------------------------------------------
// DCN weight repack: A[row=cout][k=(g*9+kt)*8+c] fragments.
// wdf[((s*4+mt)*64+lane)*8+j], s = K-step (0..17)
// ---------------------------------------------------------------------------
__global__ void repack_dcn_kernel(const float* __restrict__ w,
                                  unsigned short* __restrict__ wdf)
{
    int idx = blockIdx.x * 256 + threadIdx.x;
    if (idx >= 18 * 4 * 512) return;
    int j = idx & 7, lane = (idx >> 3) & 63, t = idx >> 9;
    int mt = t & 3, s = t >> 2;
    int cout = mt * 16 + (lane & 15);
    int kglob = s * 32 + (lane >> 4) * 8 + j;
    int gk = kglob >> 3, c = kglob & 7;
    int g = gk / 9, kt = gk - g * 9;
    wdf[idx] = f2bf(w[((size_t)cout * NF + g * 8 + c) * 9 + kt]);
}

// ---------------------------------------------------------------------------
// Extract nbr channels (0..63) from NHWC128 -> compact NHWC64 (fallback path)
// ---------------------------------------------------------------------------
__global__ void extract_nbr_kernel(const unsigned short* __restrict__ nhwcin,
                                   unsigned short* __restrict__ nbr64)
{
    int i = blockIdx.x * 256 + threadIdx.x;         // int4 units
    int p = i >> 3, c = i & 7;
    *((int4*)nbr64 + (size_t)p * 8 + c) =
        *((const int4*)(nhwcin + (size_t)p * 128) + c);
}

// ---------------------------------------------------------------------------
// Implicit-GEMM 3x3 conv via mfma_f32_16x16x32_bf16.
// ---------------------------------------------------------------------------
template <int CIN, int MGROUPS, int COUT, bool LRELU, bool OUTBF16, int NT>
__global__ __launch_bounds__(256) void conv_mfma_kernel(
    const unsigned short* __restrict__ in,
    const unsigned short* __restrict__ wf,
    const float* __restrict__ bias,
    void* __restrict__ dstv)
{
    const int tid = threadIdx.x;
    const int lane = tid & 63;
    const int wv = tid >> 6;
    const int mg = (MGROUPS == 1) ? 0 : wv;
    const int ng = (MGROUPS == 1) ? (blockIdx.x * 4 + wv) : blockIdx.x;
    constexpr int SEG = 128 / (16 * NT);
    const int x0 = (ng % SEG) * (16 * NT);
    const int y  = (ng / SEG) % 128;
    const int b  = ng / (SEG * 128);
    const int ln = lane & 15, kb = lane >> 4;
    constexpr int MT = MGROUPS * 4;

    f32x4 acc[4][NT];
#pragma unroll
    for (int i = 0; i < 4; ++i)
#pragma unroll
        for (int j = 0; j < NT; ++j) acc[i][j] = f32x4{0.f, 0.f, 0.f, 0.f};

    const unsigned short* inb = in + (size_t)b * HWSZ * CIN + (size_t)kb * 8;

    for (int c0 = 0; c0 < CIN; c0 += 32) {
#pragma unroll
        for (int tap = 0; tap < 9; ++tap) {
            const int ky = tap / 3, kx = tap % 3;
            const int yy = y + ky - 1;
            const bool rowv = (unsigned)yy < (unsigned)HH;
            const int yc = rowv ? yy : 0;
            const unsigned short* rowp = inb + (size_t)yc * WWID * CIN + c0;
            bf16x8 bfrag[NT];
#pragma unroll
            for (int nt = 0; nt < NT; ++nt) {
                int xx = x0 + nt * 16 + ln + kx - 1;
                bool v = rowv && ((unsigned)xx < (unsigned)WWID);
                int xc = v ? xx : 0;
                int4 t = *(const int4*)(rowp + (size_t)xc * CIN);
                if (!v) { t.x = 0; t.y = 0; t.z = 0; t.w = 0; }
                bfrag[nt] = *(bf16x8*)&t;
            }
            const int kt = (c0 / 32) * 9 + tap;
            const bf16x8* af = (const bf16x8*)wf + ((size_t)kt * MT + mg * 4) * 64 + lane;
            bf16x8 afrag[4];
#pragma unroll
            for (int mt = 0; mt < 4; ++mt) afrag[mt] = af[(size_t)mt * 64];
#pragma unroll
            for (int mt = 0; mt < 4; ++mt)
#pragma unroll
                for (int nt = 0; nt < NT; ++nt)
                    acc[mt][nt] = __builtin_amdgcn_mfma_f32_16x16x32_bf16(
                        afrag[mt], bfrag[nt], acc[mt][nt], 0, 0, 0);
        }
    }

#pragma unroll
    for (int mt = 0; mt < 4; ++mt) {
        const int cout = mg * 64 + mt * 16 + kb * 4;
        if (cout >= COUT) continue;
        const float b0 = bias[cout], b1 = bias[cout + 1];
        const float b2 = bias[cout + 2], b3 = bias[cout + 3];
#pragma unroll
        for (int nt = 0; nt < NT; ++nt) {
            const int px = x0 + nt * 16 + ln;
            const size_t pix = (size_t)b * HWSZ + (size_t)y * WWID + px;
            f32x4 v = acc[mt][nt];
            v[0] += b0; v[1] += b1; v[2] += b2; v[3] += b3;
            if (LRELU) {
#pragma unroll
                for (int r = 0; r < 4; ++r) v[r] = (v[r] >= 0.f) ? v[r] : 0.1f * v[r];
            }
            if (OUTBF16) {
                unsigned short* dst = (unsigned short*)dstv + pix * COUT + cout;
                int2 pk;
                pk.x = (int)f2bf(v[0]) | ((int)f2bf(v[1]) << 16);
                pk.y = (int)f2bf(v[2]) | ((int)f2bf(v[3]) << 16);
                *(int2*)dst = pk;
            } else {
                float* dst = (float*)dstv + pix * COUT + cout;
                *(f32x4*)dst = v;
            }
        }
    }
}

// ---------------------------------------------------------------------------
// DCN via MFMA: per wave M=64 couts x N=16 pixels, K split across wave pairs.
// Lane (ln,kb) bilinear-samples pixel x0+ln for (g,kt)=s*4+kb -> B-fragment.
// ---------------------------------------------------------------------------
template <bool OMBF16, int NBSTRIDE>
__global__ __launch_bounds__(256) void dcn_mfma_kernel(
    const unsigned short* __restrict__ nbrh,   // NHWC bf16, stride NBSTRIDE
    const void* __restrict__ omv,              // NHWC [216] f32 or bf16
    const unsigned short* __restrict__ wdf,    // A fragments
    const float* __restrict__ bdcn,
    float* __restrict__ out)
{
    __shared__ float red[2][64][17];
    const int tid = threadIdx.x;
    const int lane = tid & 63;
    const int wv = tid >> 6;               // 0..3
    const int pg = wv & 1, kh = wv >> 1;   // pixel-group, K-half
    const int ln = lane & 15, kb = lane >> 4;
    const int blk = blockIdx.x;            // 0..2047
    const int b = blk >> 9;
    const int rem = blk & 511;
    const int y = rem >> 2;
    const int x = ((rem & 3) << 5) + (pg << 4) + ln;

    f32x4 acc[4];
#pragma unroll
    for (int mt = 0; mt < 4; ++mt) acc[mt] = f32x4{0.f, 0.f, 0.f, 0.f};

    const size_t pixbase = (size_t)b * HWSZ;
    const size_t pm = (pixbase + (size_t)y * WWID + x) * C_OM;
    const float* omf = (const float*)omv;
    const unsigned short* omh = (const unsigned short*)omv;
    const unsigned short* gb0 = nbrh + pixbase * NBSTRIDE;

    const int s_beg = kh * 9, s_end = s_beg + 9;
    for (int s = s_beg; s < s_end; ++s) {
        const int gk = s * 4 + kb;
        const int g = gk / 9;
        const int kt = gk - g * 9;

        float oy, ox, mr;
        if (OMBF16) {
            oy = bf2f(omh[pm + gk]);
            ox = bf2f(omh[pm + 72 + gk]);
            mr = bf2f(omh[pm + 144 + gk]);
        } else {
            oy = omf[pm + gk];
            ox = omf[pm + 72 + gk];
            mr = omf[pm + 144 + gk];
        }
        const float mv = 1.f / (1.f + __expf(-mr));

        const float pyf = (float)(y + kt / 3 - 1) + oy;
        const float pxf = (float)(x + kt % 3 - 1) + ox;
        const float fy = floorf(pyf), fx = floorf(pxf);
        const float wy = pyf - fy, wx = pxf - fx;
        const int iy = (int)fy, ix = (int)fx;

        float w00 = (1.f - wy) * (1.f - wx);
        float w01 = (1.f - wy) * wx;
        float w10 = wy * (1.f - wx);
        float w11 = wy * wx;

        const bool vy0 = (iy >= 0) && (iy < HH);
        const bool vy1 = (iy + 1 >= 0) && (iy + 1 < HH);
        const bool vx0 = (ix >= 0) && (ix < WWID);
        const bool vx1 = (ix + 1 >= 0) && (ix + 1 < WWID);
        w00 *= (vy0 && vx0) ? mv : 0.f;
        w01 *= (vy0 && vx1) ? mv : 0.f;
        w10 *= (vy1 && vx0) ? mv : 0.f;
        w11 *= (vy1 && vx1) ? mv : 0.f;

        const int y0c = min(max(iy, 0), HH - 1);
        const int y1c = min(max(iy + 1, 0), HH - 1);
        const int x0c = min(max(ix, 0), WWID - 1);
        const int x1c = min(max(ix + 1, 0), WWID - 1);
        const int i00 = y0c * WWID + x0c, i01 = y0c * WWID + x1c;
        const int i10 = y1c * WWID + x0c, i11 = y1c * WWID + x1c;

        const unsigned short* gb = gb0 + g * 8;
        int4 r00 = *(const int4*)(gb + (size_t)i00 * NBSTRIDE);
        int4 r01 = *(const int4*)(gb + (size_t)i01 * NBSTRIDE);
        int4 r10 = *(const int4*)(gb + (size_t)i10 * NBSTRIDE);
        int4 r11 = *(const int4*)(gb + (size_t)i11 * NBSTRIDE);
        const unsigned short* p00 = (const unsigned short*)&r00;
        const unsigned short* p01 = (const unsigned short*)&r01;
        const unsigned short* p10 = (const unsigned short*)&r10;
        const unsigned short* p11 = (const unsigned short*)&r11;

        union { bf16x8 v; unsigned short u[8]; } bp;
#pragma unroll
        for (int c = 0; c < 8; ++c) {
            float sv = w00 * bf2f(p00[c]) + w01 * bf2f(p01[c])
                     + w10 * bf2f(p10[c]) + w11 * bf2f(p11[c]);
            bp.u[c] = f2bf(sv);
        }

        const bf16x8* af = (const bf16x8*)wdf + ((size_t)s * 4) * 64 + lane;
#pragma unroll
        for (int mt = 0; mt < 4; ++mt)
            acc[mt] = __builtin_amdgcn_mfma_f32_16x16x32_bf16(
                af[(size_t)mt * 64], bp.v, acc[mt], 0, 0, 0);
    }

    if (kh == 1) {
#pragma unroll
        for (int mt = 0; mt < 4; ++mt)
#pragma unroll
            for (int r = 0; r < 4; ++r)
                red[pg][mt * 16 + kb * 4 + r][ln] = acc[mt][r];
    }
    __syncthreads();
    if (kh == 0) {
#pragma unroll
        for (int mt = 0; mt < 4; ++mt) {
#pragma unroll
            for (int r = 0; r < 4; ++r) {
                const int cout = mt * 16 + kb * 4 + r;
                float v = acc[mt][r] + red[pg][cout][ln] + bdcn[cout];
                v = (v >= 0.f) ? v : 0.1f * v;
                out[((size_t)(b * NF + cout)) * HWSZ + (size_t)y * WWID + x] = v;
            }
        }
    }
}

// ---------------------------------------------------------------------------
extern "C" void kernel_launch(void* const* d_in, const int* in_sizes, int n_in,
                              void* d_out, int out_size, void* d_ws, size_t ws_size,
                              hipStream_t stream)
{
    const float* nbr  = (const float*)d_in[0];
    const float* ref  = (const float*)d_in[1];
    const float* w1   = (const float*)d_in[2];
    const float* b1   = (const float*)d_in[3];
    const float* wom  = (const float*)d_in[4];
    const float* bom  = (const float*)d_in[5];
    const float* wdcn = (const float*)d_in[6];
    const float* bdcn = (const float*)d_in[7];
    float* out = (float*)d_out;

    const size_t NH_B  = (size_t)BB * HWSZ * 128 * 2;   // 16,777,216
    const size_t OMF_B = (size_t)BB * HWSZ * C_OM * 4;  // 56,623,104
    const size_t OMH_B = (size_t)BB * HWSZ * C_OM * 2;  // 28,311,552
    const size_t OFF_B = (size_t)BB * HWSZ * NF * 2;    //  8,388,608
    const size_t WF1_B = 36 * 4 * 512 * 2;              //    147,456
    const size_t WF2_B = 18 * 16 * 512 * 2;             //    294,912
    char* ws = (char*)d_ws;

    const bool big = ws_size >= NH_B + OMF_B + OFF_B + WF1_B + WF2_B + (1u << 20);

    if (big) {
        unsigned short* nhwcin = (unsigned short*)ws;
        float*          om     = (float*)(ws + NH_B);
        unsigned short* off_f  = (unsigned short*)(ws + NH_B + OMF_B);
        unsigned short* wf1    = (unsigned short*)(ws + NH_B + OMF_B + OFF_B);
        unsigned short* wf2    = wf1 + WF1_B / 2;
        unsigned short* wdf    = wf2 + WF2_B / 2;

        to_nhwc_kernel<<<BB * HH * 2, 256, 0, stream>>>(nbr, ref, nhwcin);
        repack_conv_kernel<128, NF, 4><<<288, 256, 0, stream>>>(w1, wf1);
        repack_conv_kernel<64, C_OM, 16><<<576, 256, 0, stream>>>(wom, wf2);
        repack_dcn_kernel<<<144, 256, 0, stream>>>(wdcn, wdf);

        conv_mfma_kernel<128, 1, NF, true, true, 2><<<512, 256, 0, stream>>>(
            nhwcin, wf1, b1, off_f);
        conv_mfma_kernel<64, 4, C_OM, false, false, 4><<<1024, 256, 0, stream>>>(
            off_f, wf2, bom, om);
        dcn_mfma_kernel<false, 128><<<2048, 256, 0, stream>>>(
            nhwcin, om, wdf, bdcn, out);
    } else {
        // guaranteed-fit layout: om bf16 aliases nhwcin region
        unsigned short* nhwcin = (unsigned short*)ws;
        unsigned short* om     = (unsigned short*)ws;
        unsigned short* off_f  = (unsigned short*)(ws + OMH_B);
        unsigned short* nbr64  = (unsigned short*)(ws + OMH_B + OFF_B);
        unsigned short* wf1    = (unsigned short*)(ws + OMH_B + OFF_B + OFF_B);
        unsigned short* wf2    = wf1 + WF1_B / 2;
        unsigned short* wdf    = wf2 + WF2_B / 2;

        to_nhwc_kernel<<<BB * HH * 2, 256, 0, stream>>>(nbr, ref, nhwcin);
        repack_conv_kernel<128, NF, 4><<<288, 256, 0, stream>>>(w1, wf1);
        repack_conv_kernel<64, C_OM, 16><<<576, 256, 0, stream>>>(wom, wf2);
        repack_dcn_kernel<<<144, 256, 0, stream>>>(wdcn, wdf);

        conv_mfma_kernel<128, 1, NF, true, true, 2><<<512, 256, 0, stream>>>(
            nhwcin, wf1, b1, off_f);
        extract_nbr_kernel<<<2048, 256, 0, stream>>>(nhwcin, nbr64);
        conv_mfma_kernel<64, 4, C_OM, false, true, 4><<<1024, 256, 0, stream>>>(
            off_f, wf2, bom, om);
        dcn_mfma_kernel<true, 64><<<2048, 256, 0, stream>>>(
            nbr64, om, wdf, bdcn, out);
    }
}

// Round 4
// 160.367 us; speedup vs baseline: 6.1002x; 1.1474x over previous
//
#include <hip/hip_runtime.h>
#include <hip/hip_bf16.h>
#include <cmath>

#define NF 64
#define GRP 8
#define CG 8
#define KK 9
#define HH 128
#define WWID 128
#define BB 4
#define HWSZ (HH * WWID)
#define C_OM 216

typedef __attribute__((ext_vector_type(8))) short bf16x8;
typedef __attribute__((ext_vector_type(4))) float f32x4;

__device__ inline unsigned short f2bf(float f) {
    union { float f; unsigned u; } x; x.f = f;
    unsigned r = x.u + 0x7fff + ((x.u >> 16) & 1);   // RNE
    return (unsigned short)(r >> 16);
}
__device__ inline float bf2f(unsigned short s) {
    union { unsigned u; float f; } x; x.u = ((unsigned)s) << 16; return x.f;
}

// ---------------------------------------------------------------------------
// NCHW fp32 (nbr ++ ref) -> NHWC bf16 [B][H][W][128]  AND compact
// nbr-only NHWC bf16 [B][H][W][64] (for DCN gathers).
// ---------------------------------------------------------------------------
__global__ __launch_bounds__(256) void to_nhwc_kernel(
    const float* __restrict__ nbr, const float* __restrict__ ref,
    unsigned short* __restrict__ out, unsigned short* __restrict__ out64)
{
    __shared__ unsigned short lds[64 * 132];
    const int tid = threadIdx.x, blk = blockIdx.x;
    const int b = blk >> 8, rem = blk & 255, y = rem >> 1, x0 = (rem & 1) * 64;
    const size_t rowoff = (size_t)y * WWID + x0;

    for (int it = 0; it < 32; ++it) {
        int idx = it * 256 + tid;
        int c = idx >> 6, p = idx & 63;
        const float* src = (c < NF) ? (nbr + (size_t)(b * NF + c) * HWSZ)
                                    : (ref + (size_t)(b * NF + c - NF) * HWSZ);
        lds[p * 132 + c] = f2bf(src[rowoff + p]);
    }
    __syncthreads();
    const int p = tid >> 2, c0 = (tid & 3) * 32;
    unsigned short* dst = out + ((size_t)b * HWSZ + rowoff + p) * 128 + c0;
#pragma unroll
    for (int i = 0; i < 8; ++i)
        *(int2*)(dst + i * 4) = *(const int2*)&lds[p * 132 + c0 + i * 4];
    if (c0 < 64) {
        unsigned short* dst2 = out64 + ((size_t)b * HWSZ + rowoff + p) * 64 + c0;
#pragma unroll
        for (int i = 0; i < 8; ++i)
            *(int2*)(dst2 + i * 4) = *(const int2*)&lds[p * 132 + c0 + i * 4];
    }
}

// ---------------------------------------------------------------------------
// Conv weight repack OIHW fp32 -> A-fragment bf16
// wf[((kt*MT + mt)*64 + lane)*8 + j], kt = (cin0/32)*9 + tap
// ---------------------------------------------------------------------------
template <int CIN, int COUT, int MT>
__global__ void repack_conv_kernel(const float* __restrict__ w,
                                   unsigned short* __restrict__ wf)
{
    constexpr int KT = (CIN / 32) * 9;
    int idx = blockIdx.x * 256 + threadIdx.x;
    if (idx >= KT * MT * 512) return;
    int j = idx & 7, lane = (idx >> 3) & 63, t = idx >> 9;
    int mt = t % MT, kt = t / MT;
    int c0 = (kt / 9) * 32, tap = kt - (kt / 9) * 9;
    int cout = mt * 16 + (lane & 15);
    int cin = c0 + ((lane >> 4) * 8) + j;
    float v = (cout < COUT) ? w[((size_t)cout * CIN + cin) * KK + tap] : 0.f;
    wf[idx] = f2bf(v);
}

// ---------------------------------------------------------------------------
// DCN weight repack: A[row=cout][k=(g*9+kt)*8+c], wdf[((s*4+mt)*64+lane)*8+j]
// ---------------------------------------------------------------------------
__global__ void repack_dcn_kernel(const float* __restrict__ w,
                                  unsigned short* __restrict__ wdf)
{
    int idx = blockIdx.x * 256 + threadIdx.x;
    if (idx >= 18 * 4 * 512) return;
    int j = idx & 7, lane = (idx >> 3) & 63, t = idx >> 9;
    int mt = t & 3, s = t >> 2;
    int cout = mt * 16 + (lane & 15);
    int kglob = s * 32 + (lane >> 4) * 8 + j;
    int gk = kglob >> 3, c = kglob & 7;
    int g = gk / 9, kt = gk - g * 9;
    wdf[idx] = f2bf(w[((size_t)cout * NF + g * 8 + c) * 9 + kt]);
}

// ---------------------------------------------------------------------------
// Implicit-GEMM 3x3 conv (conv1) via mfma_f32_16x16x32_bf16.
// ---------------------------------------------------------------------------
template <int CIN, int COUT, bool LRELU, int NT>
__global__ __launch_bounds__(256) void conv_mfma_kernel(
    const unsigned short* __restrict__ in,
    const unsigned short* __restrict__ wf,
    const float* __restrict__ bias,
    unsigned short* __restrict__ dst)
{
    const int tid = threadIdx.x;
    const int lane = tid & 63;
    const int wv = tid >> 6;
    const int ng = blockIdx.x * 4 + wv;
    constexpr int SEG = 128 / (16 * NT);
    const int x0 = (ng % SEG) * (16 * NT);
    const int y  = (ng / SEG) % 128;
    const int b  = ng / (SEG * 128);
    const int ln = lane & 15, kb = lane >> 4;

    f32x4 acc[4][NT];
#pragma unroll
    for (int i = 0; i < 4; ++i)
#pragma unroll
        for (int j = 0; j < NT; ++j) acc[i][j] = f32x4{0.f, 0.f, 0.f, 0.f};

    const unsigned short* inb = in + (size_t)b * HWSZ * CIN + (size_t)kb * 8;

    for (int c0 = 0; c0 < CIN; c0 += 32) {
#pragma unroll
        for (int tap = 0; tap < 9; ++tap) {
            const int ky = tap / 3, kx = tap % 3;
            const int yy = y + ky - 1;
            const bool rowv = (unsigned)yy < (unsigned)HH;
            const int yc = rowv ? yy : 0;
            const unsigned short* rowp = inb + (size_t)yc * WWID * CIN + c0;
            bf16x8 bfrag[NT];
#pragma unroll
            for (int nt = 0; nt < NT; ++nt) {
                int xx = x0 + nt * 16 + ln + kx - 1;
                bool v = rowv && ((unsigned)xx < (unsigned)WWID);
                int xc = v ? xx : 0;
                int4 t = *(const int4*)(rowp + (size_t)xc * CIN);
                if (!v) { t.x = 0; t.y = 0; t.z = 0; t.w = 0; }
                bfrag[nt] = *(bf16x8*)&t;
            }
            const int kt = (c0 / 32) * 9 + tap;
            const bf16x8* af = (const bf16x8*)wf + (size_t)kt * 4 * 64 + lane;
            bf16x8 afrag[4];
#pragma unroll
            for (int mt = 0; mt < 4; ++mt) afrag[mt] = af[(size_t)mt * 64];
#pragma unroll
            for (int mt = 0; mt < 4; ++mt)
#pragma unroll
                for (int nt = 0; nt < NT; ++nt)
                    acc[mt][nt] = __builtin_amdgcn_mfma_f32_16x16x32_bf16(
                        afrag[mt], bfrag[nt], acc[mt][nt], 0, 0, 0);
        }
    }

#pragma unroll
    for (int mt = 0; mt < 4; ++mt) {
        const int cout = mt * 16 + kb * 4;
        const float b0 = bias[cout], b1 = bias[cout + 1];
        const float b2 = bias[cout + 2], b3 = bias[cout + 3];
#pragma unroll
        for (int nt = 0; nt < NT; ++nt) {
            const int px = x0 + nt * 16 + ln;
            const size_t pix = (size_t)b * HWSZ + (size_t)y * WWID + px;
            f32x4 v = acc[mt][nt];
            v[0] += b0; v[1] += b1; v[2] += b2; v[3] += b3;
            if (LRELU) {
#pragma unroll
                for (int r = 0; r < 4; ++r) v[r] = (v[r] >= 0.f) ? v[r] : 0.1f * v[r];
            }
            int2 pk;
            pk.x = (int)f2bf(v[0]) | ((int)f2bf(v[1]) << 16);
            pk.y = (int)f2bf(v[2]) | ((int)f2bf(v[3]) << 16);
            *(int2*)(dst + pix * COUT + cout) = pk;
        }
    }
}

// ---------------------------------------------------------------------------
// FUSED conv_om + DCN kernel. Block = 32 pixels (one row segment), 4 waves.
// Phase 1: om[216][32] implicit-GEMM from off_f -> LDS fp32.
// Phase 2: deformable sampling (om from LDS, gathers from compact nbr64),
//          einsum via MFMA, K split across wave pairs, LDS reduce.
// ---------------------------------------------------------------------------
#define OMSTR 225
__global__ __launch_bounds__(256) void dcn_fused_kernel(
    const unsigned short* __restrict__ off_f,   // NHWC bf16 [B][H][W][64]
    const unsigned short* __restrict__ nbr64,   // NHWC bf16 [B][H][W][64]
    const unsigned short* __restrict__ wf2,     // om A-frags (MT=14)
    const float* __restrict__ bom,
    const unsigned short* __restrict__ wdf,     // dcn A-frags
    const float* __restrict__ bdcn,
    float* __restrict__ out)
{
    __shared__ float smem[32 * OMSTR];          // 28.8 KB, reused for reduce

    const int raw = blockIdx.x;                 // 0..2047
    const int bid = (raw & 7) * 256 + (raw >> 3);   // XCD-contiguous
    const int b = bid >> 9;
    const int rem = bid & 511;
    const int y = rem >> 2;
    const int x0 = (rem & 3) * 32;

    const int tid = threadIdx.x;
    const int lane = tid & 63;
    const int wv = tid >> 6;
    const int ln = lane & 15, kb = lane >> 4;

    // ---------------- Phase 1: om GEMM (M=224 pad of 216, N=32, K=576) ----
    f32x4 acc1[4][2];
#pragma unroll
    for (int i = 0; i < 4; ++i)
#pragma unroll
        for (int j = 0; j < 2; ++j) acc1[i][j] = f32x4{0.f, 0.f, 0.f, 0.f};

    {
        const unsigned short* inb = off_f + (size_t)b * HWSZ * 64 + (size_t)kb * 8;
        for (int c0 = 0; c0 < 64; c0 += 32) {
#pragma unroll
            for (int tap = 0; tap < 9; ++tap) {
                const int ky = tap / 3, kx = tap % 3;
                const int yy = y + ky - 1;
                const bool rowv = (unsigned)yy < (unsigned)HH;
                const int yc = rowv ? yy : 0;
                const unsigned short* rowp = inb + (size_t)yc * WWID * 64 + c0;
                bf16x8 bfrag[2];
#pragma unroll
                for (int nt = 0; nt < 2; ++nt) {
                    int xx = x0 + nt * 16 + ln + kx - 1;
                    bool v = rowv && ((unsigned)xx < (unsigned)WWID);
                    int xc = v ? xx : 0;
                    int4 t = *(const int4*)(rowp + (size_t)xc * 64);
                    if (!v) { t.x = 0; t.y = 0; t.z = 0; t.w = 0; }
                    bfrag[nt] = *(bf16x8*)&t;
                }
                const int kt = (c0 / 32) * 9 + tap;
                const bf16x8* af = (const bf16x8*)wf2 + (size_t)kt * 14 * 64 + lane;
#pragma unroll
                for (int i = 0; i < 4; ++i) {
                    const int mt = wv + 4 * i;
                    if (mt < 14) {
                        bf16x8 a = af[(size_t)mt * 64];
#pragma unroll
                        for (int nt = 0; nt < 2; ++nt)
                            acc1[i][nt] = __builtin_amdgcn_mfma_f32_16x16x32_bf16(
                                a, bfrag[nt], acc1[i][nt], 0, 0, 0);
                    }
                }
            }
        }
    }

    // epilogue: om -> LDS (+bias), fp32
#pragma unroll
    for (int i = 0; i < 4; ++i) {
        const int mt = wv + 4 * i;
        if (mt >= 14) continue;
        const int cb = mt * 16 + kb * 4;
#pragma unroll
        for (int nt = 0; nt < 2; ++nt) {
            const int px = nt * 16 + ln;
#pragma unroll
            for (int r = 0; r < 4; ++r) {
                const int c = cb + r;
                if (c < C_OM) smem[px * OMSTR + c] = acc1[i][nt][r] + bom[c];
            }
        }
    }
    __syncthreads();

    // ---------------- Phase 2: deformable sampling + einsum ----------------
    const int pg = wv & 1, kh = wv >> 1;
    const int x = x0 + (pg << 4) + ln;
    const int pxl = (pg << 4) + ln;

    f32x4 acc[4];
#pragma unroll
    for (int mt = 0; mt < 4; ++mt) acc[mt] = f32x4{0.f, 0.f, 0.f, 0.f};

    const unsigned short* gb0 = nbr64 + (size_t)b * HWSZ * 64;

#pragma unroll
    for (int s2 = 0; s2 < 9; ++s2) {
        const int s = kh * 9 + s2;
        const int gk = s * 4 + kb;
        const int g = gk / 9;
        const int kt = gk - g * 9;

        const float oy = smem[pxl * OMSTR + gk];
        const float ox = smem[pxl * OMSTR + 72 + gk];
        const float mr = smem[pxl * OMSTR + 144 + gk];
        const float mv = 1.f / (1.f + __expf(-mr));

        const float pyf = (float)(y + kt / 3 - 1) + oy;
        const float pxf = (float)(x + kt % 3 - 1) + ox;
        const float fy = floorf(pyf), fx = floorf(pxf);
        const float wy = pyf - fy, wx = pxf - fx;
        const int iy = (int)fy, ix = (int)fx;

        float w00 = (1.f - wy) * (1.f - wx);
        float w01 = (1.f - wy) * wx;
        float w10 = wy * (1.f - wx);
        float w11 = wy * wx;

        const bool vy0 = (iy >= 0) && (iy < HH);
        const bool vy1 = (iy + 1 >= 0) && (iy + 1 < HH);
        const bool vx0 = (ix >= 0) && (ix < WWID);
        const bool vx1 = (ix + 1 >= 0) && (ix + 1 < WWID);
        w00 *= (vy0 && vx0) ? mv : 0.f;
        w01 *= (vy0 && vx1) ? mv : 0.f;
        w10 *= (vy1 && vx0) ? mv : 0.f;
        w11 *= (vy1 && vx1) ? mv : 0.f;

        const int y0c = min(max(iy, 0), HH - 1);
        const int y1c = min(max(iy + 1, 0), HH - 1);
        const int x0c = min(max(ix, 0), WWID - 1);
        const int x1c = min(max(ix + 1, 0), WWID - 1);
        const int i00 = y0c * WWID + x0c, i01 = y0c * WWID + x1c;
        const int i10 = y1c * WWID + x0c, i11 = y1c * WWID + x1c;

        const unsigned short* gb = gb0 + g * 8;
        int4 r00 = *(const int4*)(gb + (size_t)i00 * 64);
        int4 r01 = *(const int4*)(gb + (size_t)i01 * 64);
        int4 r10 = *(const int4*)(gb + (size_t)i10 * 64);
        int4 r11 = *(const int4*)(gb + (size_t)i11 * 64);
        const unsigned short* p00 = (const unsigned short*)&r00;
        const unsigned short* p01 = (const unsigned short*)&r01;
        const unsigned short* p10 = (const unsigned short*)&r10;
        const unsigned short* p11 = (const unsigned short*)&r11;

        union { bf16x8 v; unsigned short u[8]; } bp;
#pragma unroll
        for (int c = 0; c < 8; ++c) {
            float sv = w00 * bf2f(p00[c]) + w01 * bf2f(p01[c])
                     + w10 * bf2f(p10[c]) + w11 * bf2f(p11[c]);
            bp.u[c] = f2bf(sv);
        }

        const bf16x8* af = (const bf16x8*)wdf + ((size_t)s * 4) * 64 + lane;
#pragma unroll
        for (int mt = 0; mt < 4; ++mt)
            acc[mt] = __builtin_amdgcn_mfma_f32_16x16x32_bf16(
                af[(size_t)mt * 64], bp.v, acc[mt], 0, 0, 0);
    }

    __syncthreads();   // om_lds reads done; smem now reused as reduce buffer
    float* red = smem; // [2][64][17]
    if (kh == 1) {
#pragma unroll
        for (int mt = 0; mt < 4; ++mt)
#pragma unroll
            for (int r = 0; r < 4; ++r)
                red[(pg * 64 + mt * 16 + kb * 4 + r) * 17 + ln] = acc[mt][r];
    }
    __syncthreads();
    if (kh == 0) {
#pragma unroll
        for (int mt = 0; mt < 4; ++mt) {
#pragma unroll
            for (int r = 0; r < 4; ++r) {
                const int cout = mt * 16 + kb * 4 + r;
                float v = acc[mt][r] + red[(pg * 64 + cout) * 17 + ln] + bdcn[cout];
                v = (v >= 0.f) ? v : 0.1f * v;
                out[((size_t)(b * NF + cout)) * HWSZ + (size_t)y * WWID + x] = v;
            }
        }
    }
}

// ---------------------------------------------------------------------------
extern "C" void kernel_launch(void* const* d_in, const int* in_sizes, int n_in,
                              void* d_out, int out_size, void* d_ws, size_t ws_size,
                              hipStream_t stream)
{
    const float* nbr  = (const float*)d_in[0];
    const float* ref  = (const float*)d_in[1];
    const float* w1   = (const float*)d_in[2];
    const float* b1   = (const float*)d_in[3];
    const float* wom  = (const float*)d_in[4];
    const float* bom  = (const float*)d_in[5];
    const float* wdcn = (const float*)d_in[6];
    const float* bdcn = (const float*)d_in[7];
    float* out = (float*)d_out;

    const size_t NH_B  = (size_t)BB * HWSZ * 128 * 2;   // 16,777,216
    const size_t OFF_B = (size_t)BB * HWSZ * 64 * 2;    //  8,388,608
    const size_t N64_B = (size_t)BB * HWSZ * 64 * 2;    //  8,388,608
    const size_t WF1_B = 36 * 4 * 512 * 2;              //    147,456
    const size_t WF2_B = 18 * 14 * 512 * 2;             //    258,048

    char* ws = (char*)d_ws;
    unsigned short* nhwcin = (unsigned short*)ws;
    unsigned short* off_f  = (unsigned short*)(ws + NH_B);
    unsigned short* nbr64  = (unsigned short*)(ws + NH_B + OFF_B);
    unsigned short* wf1    = (unsigned short*)(ws + NH_B + OFF_B + N64_B);
    unsigned short* wf2    = wf1 + WF1_B / 2;
    unsigned short* wdf    = wf2 + WF2_B / 2;

    // 1) transpose: concat NHWC128 + compact nbr NHWC64
    to_nhwc_kernel<<<BB * HH * 2, 256, 0, stream>>>(nbr, ref, nhwcin, nbr64);

    // 2) weight repacks
    repack_conv_kernel<128, NF, 4><<<288, 256, 0, stream>>>(w1, wf1);
    repack_conv_kernel<64, C_OM, 14><<<504, 256, 0, stream>>>(wom, wf2);
    repack_dcn_kernel<<<144, 256, 0, stream>>>(wdcn, wdf);

    // 3) conv1: 128ch -> 64ch + lrelu, NHWC bf16
    conv_mfma_kernel<128, NF, true, 2><<<512, 256, 0, stream>>>(
        nhwcin, wf1, b1, off_f);

    // 4) fused conv_om + deformable conv
    dcn_fused_kernel<<<2048, 256, 0, stream>>>(
        off_f, nbr64, wf2, bom, wdf, bdcn, out);
}